// Round 14
// baseline (42.867 us; speedup 1.0000x reference)
//
#include <hip/hip_runtime.h>

#define N     4096
#define ON    4090
#define LDS_W 136        // 134 used + pad (rows 16B-aligned)
#define KSTR  4          // y-stripes per wave (pipeline depth)
#define NBLK  (8 * 128)  // 8 block-cols x 128 bands; consecutive blocks are
                         // x-neighbors -> coherent 4090-wide write front (merge)

__device__ __forceinline__ void gload_lds16(const float* g, float* l) {
    __builtin_amdgcn_global_load_lds(
        (const __attribute__((address_space(1))) void*)g,
        (__attribute__((address_space(3))) void*)l,
        16, 0, 0);   // 16 B/lane, dest = uniform base + lane*16
}

// Per-wave double-buffered pipelined conv. Wave owns a 128-wide column
// segment and walks 4 consecutive 8-row stripes: stage(s+1) || compute(s),
// counted s_waitcnt vmcnt(8) keeps next-stripe loads in flight (never 0
// mid-loop). No barriers, no inter-wave coupling; vertical halo re-reads
// are same-wave -> same-L2 by construction.
__global__ __launch_bounds__(256, 2)
void conv7x7_pipe(const float* __restrict__ x,
                  const float* __restrict__ w,
                  const float* __restrict__ bias,
                  float* __restrict__ out)
{
    __shared__ float lds[4 * 4096];   // 64 KB: 4 waves x 2 bufs x 2048 floats

    const int tid  = threadIdx.x;
    const int lane = tid & 63;
    const int wv   = tid >> 6;

    const int b    = blockIdx.x;
    const int bcol = b & 7;           // x position: consecutive b = x-neighbors
    const int band = b >> 3;          // 32-row band
    const int x0   = ((bcol << 2) + wv) << 7;   // wave's 128-col segment
    const int xc0  = x0 >> 2;
    float* buf0 = lds + (wv << 12);   // wave-private 4096-float region

    // weights/bias: uniform addresses -> SGPRs
    float ws[49];
    #pragma unroll
    for (int i = 0; i < 49; ++i) ws[i] = w[i];
    const float bv = bias[0];

    // stage one 15-row x 136-col stripe window (2048 floats, 8 x 1KiB DMA)
    auto stage = [&](float* buf, int y0) {
        #pragma unroll
        for (int k = 0; k < 8; ++k) {
            const int m   = (k << 6) + lane;
            const int row = m / 34;                    // magic-mul
            const int cc  = m - row * 34;
            const int gy  = min(y0 + row, N - 1);      // clamp rows (finite dup)
            const int gc  = min(xc0 + cc, (N >> 2) - 1);
            gload_lds16(x + ((size_t)gy << 12) + ((size_t)gc << 2),
                        buf + (k << 8));
        }
    };

    stage(buf0, band << 5);   // prologue: stripe 0

    const int tau   = lane & 31;
    const int rg2   = lane >> 5;
    const int colf  = tau << 2;
    const int rbase = rg2 << 2;
    const int ox    = x0 + colf;
    const bool inx  = (ox + 4 <= ON);

    #pragma unroll
    for (int s = 0; s < KSTR; ++s) {
        if (s + 1 < KSTR)
            stage(buf0 + (((s + 1) & 1) << 11), ((band << 2) + s + 1) << 3);

        // counted wait: the 8 newest outstanding are stripe s+1's loads;
        // everything older (stripe s loads, prior stores) drains.
        if (s + 1 < KSTR) asm volatile("s_waitcnt vmcnt(8)" ::: "memory");
        else              asm volatile("s_waitcnt vmcnt(0)" ::: "memory");
        __builtin_amdgcn_sched_barrier(0);   // pin: no ds_read hoists above wait

        const float* cbuf = buf0 + ((s & 1) << 11);
        const int y0 = ((band << 2) + s) << 3;

        float acc[4][4] = {};
        #pragma unroll
        for (int rr = 0; rr < 10; ++rr) {
            const float* rp = cbuf + (rbase + rr) * LDS_W + colf;
            float v[10];
            const float4 a  = *reinterpret_cast<const float4*>(rp);
            const float4 bq = *reinterpret_cast<const float4*>(rp + 4);
            const float2 c  = *reinterpret_cast<const float2*>(rp + 8);
            v[0]=a.x;  v[1]=a.y;  v[2]=a.z;  v[3]=a.w;
            v[4]=bq.x; v[5]=bq.y; v[6]=bq.z; v[7]=bq.w;
            v[8]=c.x;  v[9]=c.y;

            #pragma unroll
            for (int r = 0; r < 4; ++r) {
                const int ky = rr - r;               // compile-time after unroll
                if (ky >= 0 && ky < 7) {
                    #pragma unroll
                    for (int kx = 0; kx < 7; ++kx) {
                        const float wk = ws[ky * 7 + kx];
                        #pragma unroll
                        for (int j = 0; j < 4; ++j)
                            acc[r][j] = fmaf(v[kx + j], wk, acc[r][j]);
                    }
                }
            }
        }

        const int oy0 = y0 + rbase;
        if (inx && oy0 + 4 <= ON) {
            #pragma unroll
            for (int r = 0; r < 4; ++r) {
                float* dst = out + (size_t)(oy0 + r) * ON + ox;   // 8B-aligned
                *reinterpret_cast<float2*>(dst)     = make_float2(acc[r][0] + bv, acc[r][1] + bv);
                *reinterpret_cast<float2*>(dst + 2) = make_float2(acc[r][2] + bv, acc[r][3] + bv);
            }
        } else {
            #pragma unroll
            for (int r = 0; r < 4; ++r) {
                const int oy = oy0 + r;
                if (oy < ON) {
                    float* dst = out + (size_t)oy * ON;
                    #pragma unroll
                    for (int j = 0; j < 4; ++j) {
                        const int oxj = ox + j;
                        if (oxj < ON) dst[oxj] = acc[r][j] + bv;
                    }
                }
            }
        }
    }
}

extern "C" void kernel_launch(void* const* d_in, const int* in_sizes, int n_in,
                              void* d_out, int out_size, void* d_ws, size_t ws_size,
                              hipStream_t stream) {
    const float* x    = (const float*)d_in[0];
    const float* w    = (const float*)d_in[1];
    const float* bias = (const float*)d_in[2];
    float* out        = (float*)d_out;

    conv7x7_pipe<<<dim3(NBLK, 1, 1), dim3(256, 1, 1), 0, stream>>>(x, w, bias, out);
}

// Round 15
// 33.782 us; speedup vs baseline: 1.2689x; 1.2689x over previous
//
#include <hip/hip_runtime.h>

#define N   4096
#define ON  4090
#define LDS_W 136                 // 134 used + pad (rows 16B-aligned)
#define WBUF  2048                // floats per wave buffer = 8 KB = 8 instr * 256
#define GX  32                    // x wave-tiles per band (128 wide each)
#define GY  512                   // 8-row bands
#define NT  (GX * GY)             // 16384 wave-tiles
#define NB  (NT / 4)              // 4096 blocks

__device__ __forceinline__ void gload_lds16(const float* g, float* l) {
    __builtin_amdgcn_global_load_lds(
        (const __attribute__((address_space(1))) void*)g,
        (__attribute__((address_space(3))) void*)l,
        16, 0, 0);   // 16 B per lane, dest = uniform base + lane*16
}

// Wave-autonomous barrier-free conv (R10 structure) + LINEAR dispatch:
// wave-tile id t = 4*blockIdx+wv, row-major over 8-row bands. Consecutive
// blocks are x-adjacent (8 blocks = one full band) -> coherent write front
// -> partial 64B output lines merge in L2/L3 (R14-proven: WRITE = 1.0x).
// 32 KB LDS -> 5 blocks/CU = 20 waves/CU of independent TLP.
__global__ __launch_bounds__(256, 5)
void conv7x7_wave(const float* __restrict__ x,
                  const float* __restrict__ w,
                  const float* __restrict__ bias,
                  float* __restrict__ out)
{
    __shared__ float lds[4 * WBUF];   // 32,768 B -> 5 blocks/CU (160 KiB exact)

    const int tid  = threadIdx.x;
    const int lane = tid & 63;
    const int wv   = tid >> 6;
    float* buf = lds + (wv << 11);    // wave-private 2048-float region

    const int t  = (blockIdx.x << 2) + wv;   // wave-tile id, row-major
    const int bx = t & (GX - 1);
    const int by = t >> 5;
    const int x0 = bx << 7;           // 128-col segment base
    const int y0 = by << 3;           // 8-row stripe base

    // ---- stage 14 used (+2 overshoot) rows x 136 floats, flat chunks ----
    // 8 width-16 DMAs fill exactly WBUF. Row/col clamps engage only at the
    // image edge; clamped data feeds only store-guarded outputs.
    {
        const int xc0 = x0 >> 2;
        #pragma unroll
        for (int k = 0; k < 8; ++k) {
            const int m   = (k << 6) + lane;
            const int row = m / 34;               // magic-mul
            const int cc  = m - row * 34;
            const int gy  = min(y0 + row, N - 1);
            const int gc  = min(xc0 + cc, (N >> 2) - 1);
            gload_lds16(x + ((size_t)gy << 12) + ((size_t)gc << 2),
                        buf + (k << 8));
        }
    }

    // uniform-address weight/bias loads (scalar path) overlap the DMA
    float ws[49];
    #pragma unroll
    for (int i = 0; i < 49; ++i) ws[i] = w[i];
    const float bv = bias[0];

    // wave-local drain of the LDS DMA (replaces __syncthreads)
    asm volatile("s_waitcnt vmcnt(0)" ::: "memory");

    // ---- compute: lane = (col chunk tau, row half rg2); 4-wide x 4-tall ----
    const int tau   = lane & 31;
    const int rg2   = lane >> 5;         // 0..1 -> rows 0-3 / 4-7 of stripe
    const int colf  = tau << 2;
    const int rbase = rg2 << 2;

    float acc[4][4] = {};

    #pragma unroll
    for (int rr = 0; rr < 10; ++rr) {    // 10 input rows feed 4 output rows
        const float* rp = buf + (rbase + rr) * LDS_W + colf;
        float v[10];
        const float4 a  = *reinterpret_cast<const float4*>(rp);
        const float4 bq = *reinterpret_cast<const float4*>(rp + 4);
        const float2 c  = *reinterpret_cast<const float2*>(rp + 8);
        v[0]=a.x;  v[1]=a.y;  v[2]=a.z;  v[3]=a.w;
        v[4]=bq.x; v[5]=bq.y; v[6]=bq.z; v[7]=bq.w;
        v[8]=c.x;  v[9]=c.y;

        #pragma unroll
        for (int r = 0; r < 4; ++r) {
            const int ky = rr - r;               // compile-time after unroll
            if (ky >= 0 && ky < 7) {
                #pragma unroll
                for (int kx = 0; kx < 7; ++kx) {
                    const float wk = ws[ky * 7 + kx];
                    #pragma unroll
                    for (int j = 0; j < 4; ++j)
                        acc[r][j] = fmaf(v[kx + j], wk, acc[r][j]);
                }
            }
        }
    }

    // ---- store: unguarded float2 pairs interior, guarded scalar on edges ----
    const int ox  = x0 + colf;
    const int oy0 = y0 + rbase;
    if (ox + 4 <= ON && oy0 + 4 <= ON) {
        #pragma unroll
        for (int r = 0; r < 4; ++r) {
            float* dst = out + (size_t)(oy0 + r) * ON + ox;   // 8B-aligned
            *reinterpret_cast<float2*>(dst)     = make_float2(acc[r][0] + bv, acc[r][1] + bv);
            *reinterpret_cast<float2*>(dst + 2) = make_float2(acc[r][2] + bv, acc[r][3] + bv);
        }
    } else {
        #pragma unroll
        for (int r = 0; r < 4; ++r) {
            const int oy = oy0 + r;
            if (oy < ON) {
                float* dst = out + (size_t)oy * ON;
                #pragma unroll
                for (int j = 0; j < 4; ++j) {
                    const int oxj = ox + j;
                    if (oxj < ON) dst[oxj] = acc[r][j] + bv;
                }
            }
        }
    }
}

extern "C" void kernel_launch(void* const* d_in, const int* in_sizes, int n_in,
                              void* d_out, int out_size, void* d_ws, size_t ws_size,
                              hipStream_t stream) {
    const float* x    = (const float*)d_in[0];
    const float* w    = (const float*)d_in[1];
    const float* bias = (const float*)d_in[2];
    float* out        = (float*)d_out;

    conv7x7_wave<<<dim3(NB, 1, 1), dim3(256, 1, 1), 0, stream>>>(x, w, bias, out);
}